// Round 6
// baseline (4637.705 us; speedup 1.0000x reference)
//
#include <hip/hip_runtime.h>
#include <math.h>

#define BB   512
#define TT   256
#define HH   512
#define DIN  514
#define DOUTN 2
#define DT   0.1f

typedef short s16x8 __attribute__((ext_vector_type(8)));
typedef float f32x4 __attribute__((ext_vector_type(4)));

__device__ __forceinline__ float retanh_f(float a) {
    // retanh(a) = max(tanh(a),0); fast branchless form. For a<=0 -> 0.
    float am = fminf(a, 15.0f);
    float E  = __expf(2.0f * am);
    float tp = __fdividef(E - 1.0f, E + 1.0f);
    return a > 0.0f ? tp : 0.0f;
}

__device__ __forceinline__ unsigned short f2bf(float f) {
    // fp32 -> bf16 round-to-nearest-even
    unsigned u = __float_as_uint(f);
    unsigned r = (u + 0x7FFFu + ((u >> 16) & 1u)) >> 16;
    return (unsigned short)r;
}

// ---------------------------------------------------------------------------
// Kernel 1a: WxT[d][j] = Wx[j][d]  (for the x2ah GEMM)
// ---------------------------------------------------------------------------
__global__ __launch_bounds__(256) void transpose_wx(const float* __restrict__ Wx,
                                                    float* __restrict__ WxT) {
    int idx = blockIdx.x * 256 + threadIdx.x;
    if (idx < DIN * HH) {
        int d = idx / HH, j = idx % HH;
        WxT[idx] = Wx[j * DIN + d];
    }
}

// ---------------------------------------------------------------------------
// Kernel 1b: pack W_h into bf16 MFMA B-fragments.
// Fragment index f = (kc*32 + jt)*64 + lane; element e:
//   B[k][j] = Wh[j][k], j = jt*16 + (lane&15), k = kc*32 + (lane>>4)*8 + e.
// (The (lane-group,e)->k map only needs to MATCH the A-side map; any
//  consistent bijection sums identically over K in the MFMA.)
// ---------------------------------------------------------------------------
__global__ __launch_bounds__(256) void pack_wh(const float* __restrict__ Wh,
                                               unsigned short* __restrict__ Wp) {
    const int idx = blockIdx.x * 256 + threadIdx.x;   // 0..32767
    const int l  = idx & 63;
    const int jt = (idx >> 6) & 31;
    const int kc = idx >> 11;
    const int j  = jt * 16 + (l & 15);
    const int k0 = kc * 32 + (l >> 4) * 8;
    s16x8 pv;
    #pragma unroll
    for (int e = 0; e < 8; ++e) pv[e] = (short)f2bf(Wh[j * HH + k0 + e]);
    *(s16x8*)&Wp[(size_t)idx * 8] = pv;
}

// ---------------------------------------------------------------------------
// Kernel 2: x2ah = x @ WxT + b (fp32, into hstore region; consumed+overwritten
// by the scan). Proven round-1 kernel, near the fp32 VALU roofline.
// ---------------------------------------------------------------------------
__global__ __launch_bounds__(256) void x2ah_kernel(const float* __restrict__ X,
                                                   const float* __restrict__ WxT,
                                                   const float* __restrict__ bias,
                                                   float* __restrict__ outr) {
    __shared__ float xs[16][516];
    const int tid = threadIdx.x;
    const int r0  = blockIdx.x * 16;

    #pragma unroll
    for (int m = 0; m < 16; ++m) {
        const float* xr = X + (r0 + m) * DIN;
        xs[m][tid]       = xr[tid];
        xs[m][tid + 256] = xr[tid + 256];
        if (tid < 2) xs[m][512 + tid] = xr[512 + tid];
    }
    __syncthreads();

    const int j = 2 * tid;
    const float2 bv = *(const float2*)&bias[j];
    float acc[16][2];
    #pragma unroll
    for (int m = 0; m < 16; ++m) { acc[m][0] = bv.x; acc[m][1] = bv.y; }

    for (int d = 0; d < 512; d += 4) {
        const float2 w0 = *(const float2*)&WxT[(d + 0) * HH + j];
        const float2 w1 = *(const float2*)&WxT[(d + 1) * HH + j];
        const float2 w2 = *(const float2*)&WxT[(d + 2) * HH + j];
        const float2 w3 = *(const float2*)&WxT[(d + 3) * HH + j];
        #pragma unroll
        for (int m = 0; m < 16; ++m) {
            const float4 xv = *(const float4*)&xs[m][d];
            acc[m][0] += xv.x * w0.x; acc[m][1] += xv.x * w0.y;
            acc[m][0] += xv.y * w1.x; acc[m][1] += xv.y * w1.y;
            acc[m][0] += xv.z * w2.x; acc[m][1] += xv.z * w2.y;
            acc[m][0] += xv.w * w3.x; acc[m][1] += xv.w * w3.y;
        }
    }
    {
        const float2 wa = *(const float2*)&WxT[512 * HH + j];
        const float2 wb = *(const float2*)&WxT[513 * HH + j];
        #pragma unroll
        for (int m = 0; m < 16; ++m) {
            acc[m][0] += xs[m][512] * wa.x; acc[m][1] += xs[m][512] * wa.y;
            acc[m][0] += xs[m][513] * wb.x; acc[m][1] += xs[m][513] * wb.y;
        }
    }
    #pragma unroll
    for (int m = 0; m < 16; ++m) {
        *(float2*)&outr[(r0 + m) * HH + j] = make_float2(acc[m][0], acc[m][1]);
    }
}

// ---------------------------------------------------------------------------
// Kernel 3 (Design G): self-contained MFMA scan. 32 WGs x 512 thr, MB=16.
// Regular launch; NO cross-WG communication of any kind.
// Per step: each wave streams its 64KB slice of bf16 W from L2 (1-deep reg
// double buffer), MFMAs against the h tile in LDS, fp32 epilogue, writes h
// (fp32->HBM, bf16->LDS other buffer), one barrier.
//   A-frag: lane reads 16B of hbuf[b=lane&15][kc*32 + (lane>>4)*8 .. +8)
//   B-frag: pre-packed (pack_wh) with the SAME (lane-group,e)->k map.
//   C-frag (m89-verified): col = lane&15, row = (lane>>4)*4 + reg.
// ---------------------------------------------------------------------------
__global__ __launch_bounds__(512) void scan6_kernel(const unsigned short* __restrict__ Wp,
                                                    const float* __restrict__ noise,
                                                    const float* __restrict__ ah0,
                                                    float* __restrict__ hio) {
    __shared__ __align__(16) unsigned short hbuf[2][16][520];  // [buf][b][k], pad 520

    const int tid = threadIdx.x;
    const int l   = tid & 63;
    const int w   = tid >> 6;       // wave 0..7 -> j-tiles 4w..4w+3
    const int lm  = l & 15;
    const int lg  = l >> 4;
    const int b0  = blockIdx.x * 16;

    int jn[4];
    #pragma unroll
    for (int n = 0; n < 4; ++n) jn[n] = (4 * w + n) * 16 + lm;

    float ah[4][4];
    int   Cb[4][4];
    #pragma unroll
    for (int n = 0; n < 4; ++n) {
        #pragma unroll
        for (int r = 0; r < 4; ++r) {
            ah[n][r] = ah0[jn[n]];
            Cb[n][r] = ((b0 + lg * 4 + r) * TT) * HH + jn[n];
        }
    }

    // init h(t=0) = retanh(ah0), same for every batch row
    for (int idx = tid; idx < 16 * 512; idx += 512) {
        int b = idx >> 9, k = idx & 511;
        hbuf[0][b][k] = f2bf(retanh_f(ah0[k]));
    }
    __syncthreads();

    const s16x8* WpV = (const s16x8*)Wp;

    int cur = 0;
    for (int t = 0; t < TT; ++t) {
        // prologue prefetch: kc=0 fragments (W stream restarts immediately)
        s16x8 A[2], Bf[2][4];
        A[0] = *(const s16x8*)&hbuf[cur][lm][lg * 8];
        #pragma unroll
        for (int n = 0; n < 4; ++n)
            Bf[0][n] = WpV[(size_t)(4 * w + n) * 64 + l];

        // input drive + noise for this step (independent; hide under stream)
        float x2[4][4], nz[4][4];
        #pragma unroll
        for (int n = 0; n < 4; ++n) {
            #pragma unroll
            for (int r = 0; r < 4; ++r) {
                const int gi = Cb[n][r] + t * HH;
                x2[n][r] = hio[gi];
                nz[n][r] = noise[gi];
            }
        }

        f32x4 acc[4];
        #pragma unroll
        for (int n = 0; n < 4; ++n) acc[n] = (f32x4){0.f, 0.f, 0.f, 0.f};

        #pragma unroll
        for (int kc = 0; kc < 16; ++kc) {
            const int pc = kc & 1, nc = pc ^ 1;   // compile-time under unroll
            if (kc < 15) {
                A[nc] = *(const s16x8*)&hbuf[cur][lm][(kc + 1) * 32 + lg * 8];
                #pragma unroll
                for (int n = 0; n < 4; ++n)
                    Bf[nc][n] = WpV[(size_t)((kc + 1) * 32 + 4 * w + n) * 64 + l];
            }
            #pragma unroll
            for (int n = 0; n < 4; ++n)
                acc[n] = __builtin_amdgcn_mfma_f32_16x16x32_bf16(
                             A[pc], Bf[pc][n], acc[n], 0, 0, 0);
        }

        // epilogue: fp32 state update; h -> HBM (fp32) + LDS other buffer (bf16)
        const int nxt = cur ^ 1;
        #pragma unroll
        for (int n = 0; n < 4; ++n) {
            #pragma unroll
            for (int r = 0; r < 4; ++r) {
                float a = ah[n][r];
                a += DT * (acc[n][r] + x2[n][r] - a);
                ah[n][r] = a;
                const float h = retanh_f(a) + nz[n][r];
                hio[Cb[n][r] + t * HH] = h;
                hbuf[nxt][lg * 4 + r][jn[n]] = f2bf(h);
            }
        }
        cur = nxt;
        __syncthreads();   // h(t+1) visible before next step's A reads
    }
}

// ---------------------------------------------------------------------------
// Kernel 4: tiny output projection
// ---------------------------------------------------------------------------
__global__ __launch_bounds__(256) void out_kernel(const float* __restrict__ hstore,
                                                  const float* __restrict__ Wy,
                                                  float* __restrict__ out0) {
    const int wave = threadIdx.x >> 6;
    const int lane = threadIdx.x & 63;
    const int r = blockIdx.x * 4 + wave;

    const float4* hv4 = (const float4*)&hstore[r * HH];
    float a0 = 0.0f, a1 = 0.0f;
    #pragma unroll
    for (int u = 0; u < 2; ++u) {
        const int e = u * 64 + lane;
        const float4 h  = hv4[e];
        const float4 w0 = *(const float4*)&Wy[e * 4];
        const float4 w1 = *(const float4*)&Wy[HH + e * 4];
        a0 += h.x * w0.x + h.y * w0.y + h.z * w0.z + h.w * w0.w;
        a1 += h.x * w1.x + h.y * w1.y + h.z * w1.z + h.w * w1.w;
    }
    #pragma unroll
    for (int off = 32; off > 0; off >>= 1) {
        a0 += __shfl_xor(a0, off);
        a1 += __shfl_xor(a1, off);
    }
    if (lane == 0) {
        out0[r * 2]     = a0;
        out0[r * 2 + 1] = a1;
    }
}

// ---------------------------------------------------------------------------
extern "C" void kernel_launch(void* const* d_in, const int* in_sizes, int n_in,
                              void* d_out, int out_size, void* d_ws, size_t ws_size,
                              hipStream_t stream) {
    const float* x     = (const float*)d_in[0];  // [B,T,DIN]
    const float* noise = (const float*)d_in[1];  // [B,T,H]
    const float* Wx    = (const float*)d_in[2];  // [H,DIN]
    const float* bah   = (const float*)d_in[3];  // [H]
    const float* Wh    = (const float*)d_in[4];  // [H,H]
    const float* Wy    = (const float*)d_in[5];  // [DOUT,H]
    const float* ah0   = (const float*)d_in[6];  // [H]

    float* out0   = (float*)d_out;                   // [B,T,DOUT]
    float* hstore = (float*)d_out + BB * TT * DOUTN; // [B,T,H]

    float* WxT = (float*)d_ws;                          // [DIN,H] fp32, 1.05 MB
    unsigned short* Wp = (unsigned short*)(WxT + DIN * HH);  // [512*512] bf16, 512 KB

    transpose_wx<<<(DIN * HH + 255) / 256, 256, 0, stream>>>(Wx, WxT);
    pack_wh<<<16 * 32 * 64 / 256, 256, 0, stream>>>(Wh, Wp);
    x2ah_kernel<<<BB * TT / 16, 256, 0, stream>>>(x, WxT, bah, hstore);
    scan6_kernel<<<BB / 16, 512, 0, stream>>>(Wp, noise, ah0, hstore);
    out_kernel<<<BB * TT / 4, 256, 0, stream>>>(hstore, Wy, out0);
}

// Round 7
// 2720.564 us; speedup vs baseline: 1.7047x; 1.7047x over previous
//
#include <hip/hip_runtime.h>
#include <math.h>

#define BB   512
#define TT   256
#define HH   512
#define DIN  514
#define DOUTN 2
#define DT   0.1f

typedef short s16x8 __attribute__((ext_vector_type(8)));
typedef float f32x4 __attribute__((ext_vector_type(4)));

__device__ __forceinline__ float retanh_f(float a) {
    float am = fminf(a, 15.0f);
    float E  = __expf(2.0f * am);
    float tp = __fdividef(E - 1.0f, E + 1.0f);
    return a > 0.0f ? tp : 0.0f;
}

__device__ __forceinline__ unsigned short f2bf(float f) {
    unsigned u = __float_as_uint(f);
    unsigned r = (u + 0x7FFFu + ((u >> 16) & 1u)) >> 16;
    return (unsigned short)r;
}

// ---------------------------------------------------------------------------
// Kernel 1a: WxT[d][j] = Wx[j][d]
// ---------------------------------------------------------------------------
__global__ __launch_bounds__(256) void transpose_wx(const float* __restrict__ Wx,
                                                    float* __restrict__ WxT) {
    int idx = blockIdx.x * 256 + threadIdx.x;
    if (idx < DIN * HH) {
        int d = idx / HH, j = idx % HH;
        WxT[idx] = Wx[j * DIN + d];
    }
}

// ---------------------------------------------------------------------------
// Kernel 1b: pack W_h into bf16 MFMA B-fragments (PROVEN in round 6).
// frag f = (kc*32 + jt)*64 + lane, elem e: B[k][j]=Wh[j][k],
//   j = jt*16 + (lane&15), k = kc*32 + (lane>>4)*8 + e.
// ---------------------------------------------------------------------------
__global__ __launch_bounds__(256) void pack_wh(const float* __restrict__ Wh,
                                               unsigned short* __restrict__ Wp) {
    const int idx = blockIdx.x * 256 + threadIdx.x;   // 0..32767
    const int l  = idx & 63;
    const int jt = (idx >> 6) & 31;
    const int kc = idx >> 11;
    const int j  = jt * 16 + (l & 15);
    const int k0 = kc * 32 + (l >> 4) * 8;
    s16x8 pv;
    #pragma unroll
    for (int e = 0; e < 8; ++e) pv[e] = (short)f2bf(Wh[j * HH + k0 + e]);
    *(s16x8*)&Wp[(size_t)idx * 8] = pv;
}

// ---------------------------------------------------------------------------
// Kernel 2: x2ah = x @ WxT + b (fp32; into hstore region, consumed by scan)
// ---------------------------------------------------------------------------
__global__ __launch_bounds__(256) void x2ah_kernel(const float* __restrict__ X,
                                                   const float* __restrict__ WxT,
                                                   const float* __restrict__ bias,
                                                   float* __restrict__ outr) {
    __shared__ float xs[16][516];
    const int tid = threadIdx.x;
    const int r0  = blockIdx.x * 16;

    #pragma unroll
    for (int m = 0; m < 16; ++m) {
        const float* xr = X + (r0 + m) * DIN;
        xs[m][tid]       = xr[tid];
        xs[m][tid + 256] = xr[tid + 256];
        if (tid < 2) xs[m][512 + tid] = xr[512 + tid];
    }
    __syncthreads();

    const int j = 2 * tid;
    const float2 bv = *(const float2*)&bias[j];
    float acc[16][2];
    #pragma unroll
    for (int m = 0; m < 16; ++m) { acc[m][0] = bv.x; acc[m][1] = bv.y; }

    for (int d = 0; d < 512; d += 4) {
        const float2 w0 = *(const float2*)&WxT[(d + 0) * HH + j];
        const float2 w1 = *(const float2*)&WxT[(d + 1) * HH + j];
        const float2 w2 = *(const float2*)&WxT[(d + 2) * HH + j];
        const float2 w3 = *(const float2*)&WxT[(d + 3) * HH + j];
        #pragma unroll
        for (int m = 0; m < 16; ++m) {
            const float4 xv = *(const float4*)&xs[m][d];
            acc[m][0] += xv.x * w0.x; acc[m][1] += xv.x * w0.y;
            acc[m][0] += xv.y * w1.x; acc[m][1] += xv.y * w1.y;
            acc[m][0] += xv.z * w2.x; acc[m][1] += xv.z * w2.y;
            acc[m][0] += xv.w * w3.x; acc[m][1] += xv.w * w3.y;
        }
    }
    {
        const float2 wa = *(const float2*)&WxT[512 * HH + j];
        const float2 wb = *(const float2*)&WxT[513 * HH + j];
        #pragma unroll
        for (int m = 0; m < 16; ++m) {
            acc[m][0] += xs[m][512] * wa.x; acc[m][1] += xs[m][512] * wa.y;
            acc[m][0] += xs[m][513] * wb.x; acc[m][1] += xs[m][513] * wb.y;
        }
    }
    #pragma unroll
    for (int m = 0; m < 16; ++m) {
        *(float2*)&outr[(r0 + m) * HH + j] = make_float2(acc[m][0], acc[m][1]);
    }
}

// ---------------------------------------------------------------------------
// Kernel 3 (Design H): MFMA scan with W fully resident.
// 32 WGs x 512 thr (8 waves), 1 WG/CU, __launch_bounds__(512,2) -> 256 VGPR.
// Wave w owns j-tiles 4w..4w+3. W fragments: kc 4..15 in 48 s16x8 registers
// (192 VGPRs, static-indexed), kc 0..3 in 128 KB LDS. h single-buffered in
// LDS (bf16, 16x520). Steady state: ZERO vmem in the GEMM; only x2/nz HBM
// loads (issued at step start, consumed in epilogue). 2 barriers/step.
// Fragment maps identical to proven scan6.
// ---------------------------------------------------------------------------
__global__ __launch_bounds__(512, 2) void scan7_kernel(const unsigned short* __restrict__ Wp,
                                                       const float* __restrict__ noise,
                                                       const float* __restrict__ ah0,
                                                       float* __restrict__ hio) {
    __shared__ __align__(16) unsigned short Wl[4 * 32 * 64 * 8];  // 128 KB: kc 0..3
    __shared__ __align__(16) unsigned short hs[16][520];          // 16.6 KB

    const int tid = threadIdx.x;
    const int l   = tid & 63;
    const int w   = tid >> 6;
    const int lm  = l & 15;
    const int lg  = l >> 4;
    const int b0  = blockIdx.x * 16;

    const s16x8* WpV = (const s16x8*)Wp;
    s16x8* WlV = (s16x8*)Wl;

    // ---- one-time: W into LDS (kc 0..3) and registers (kc 4..15) ----
    for (int idx = tid; idx < 4 * 32 * 64; idx += 512)
        WlV[idx] = WpV[idx];

    s16x8 Wreg[48];
    #pragma unroll
    for (int kc = 0; kc < 12; ++kc) {
        #pragma unroll
        for (int n = 0; n < 4; ++n)
            Wreg[kc * 4 + n] = WpV[(size_t)((kc + 4) * 32 + 4 * w + n) * 64 + l];
    }

    int jn[4];
    #pragma unroll
    for (int n = 0; n < 4; ++n) jn[n] = (4 * w + n) * 16 + lm;

    float ah[4][4];
    int   Cb[4][4];
    #pragma unroll
    for (int n = 0; n < 4; ++n) {
        #pragma unroll
        for (int r = 0; r < 4; ++r) {
            ah[n][r] = ah0[jn[n]];
            Cb[n][r] = ((b0 + lg * 4 + r) * TT) * HH + jn[n];
        }
    }

    // init h(t=0) = retanh(ah0), same for all batch rows
    for (int idx = tid; idx < 16 * 512; idx += 512) {
        int b = idx >> 9, k = idx & 511;
        hs[b][k] = f2bf(retanh_f(ah0[k]));
    }
    __syncthreads();

    for (int t = 0; t < TT; ++t) {
        // issue this step's input-drive + noise loads (hidden under the GEMM)
        float x2[4][4], nz[4][4];
        #pragma unroll
        for (int n = 0; n < 4; ++n) {
            #pragma unroll
            for (int r = 0; r < 4; ++r) {
                const int gi = Cb[n][r] + t * HH;
                x2[n][r] = hio[gi];
                nz[n][r] = noise[gi];
            }
        }

        f32x4 acc[4];
        #pragma unroll
        for (int n = 0; n < 4; ++n) acc[n] = (f32x4){0.f, 0.f, 0.f, 0.f};

        // ---- kc 0..3: B from LDS ----
        #pragma unroll
        for (int kc = 0; kc < 4; ++kc) {
            const s16x8 A = *(const s16x8*)&hs[lm][kc * 32 + lg * 8];
            #pragma unroll
            for (int n = 0; n < 4; ++n) {
                const s16x8 Bf = WlV[(size_t)(kc * 32 + 4 * w + n) * 64 + l];
                acc[n] = __builtin_amdgcn_mfma_f32_16x16x32_bf16(A, Bf, acc[n], 0, 0, 0);
            }
        }
        // ---- kc 4..15: B from registers (no memory at all) ----
        #pragma unroll
        for (int kc = 0; kc < 12; ++kc) {
            const s16x8 A = *(const s16x8*)&hs[lm][(kc + 4) * 32 + lg * 8];
            #pragma unroll
            for (int n = 0; n < 4; ++n)
                acc[n] = __builtin_amdgcn_mfma_f32_16x16x32_bf16(A, Wreg[kc * 4 + n],
                                                                 acc[n], 0, 0, 0);
        }

        __syncthreads();   // all reads of hs(t) complete

        // ---- epilogue: fp32 state update; h -> HBM (fp32) + hs (bf16) ----
        #pragma unroll
        for (int n = 0; n < 4; ++n) {
            #pragma unroll
            for (int r = 0; r < 4; ++r) {
                float a = ah[n][r];
                a += DT * (acc[n][r] + x2[n][r] - a);
                ah[n][r] = a;
                const float h = retanh_f(a) + nz[n][r];
                hio[Cb[n][r] + t * HH] = h;
                hs[lg * 4 + r][jn[n]] = f2bf(h);
            }
        }
        __syncthreads();   // hs(t+1) complete before next step's reads
    }
}

// ---------------------------------------------------------------------------
// Kernel 4: tiny output projection
// ---------------------------------------------------------------------------
__global__ __launch_bounds__(256) void out_kernel(const float* __restrict__ hstore,
                                                  const float* __restrict__ Wy,
                                                  float* __restrict__ out0) {
    const int wave = threadIdx.x >> 6;
    const int lane = threadIdx.x & 63;
    const int r = blockIdx.x * 4 + wave;

    const float4* hv4 = (const float4*)&hstore[r * HH];
    float a0 = 0.0f, a1 = 0.0f;
    #pragma unroll
    for (int u = 0; u < 2; ++u) {
        const int e = u * 64 + lane;
        const float4 h  = hv4[e];
        const float4 w0 = *(const float4*)&Wy[e * 4];
        const float4 w1 = *(const float4*)&Wy[HH + e * 4];
        a0 += h.x * w0.x + h.y * w0.y + h.z * w0.z + h.w * w0.w;
        a1 += h.x * w1.x + h.y * w1.y + h.z * w1.z + h.w * w1.w;
    }
    #pragma unroll
    for (int off = 32; off > 0; off >>= 1) {
        a0 += __shfl_xor(a0, off);
        a1 += __shfl_xor(a1, off);
    }
    if (lane == 0) {
        out0[r * 2]     = a0;
        out0[r * 2 + 1] = a1;
    }
}

// ---------------------------------------------------------------------------
extern "C" void kernel_launch(void* const* d_in, const int* in_sizes, int n_in,
                              void* d_out, int out_size, void* d_ws, size_t ws_size,
                              hipStream_t stream) {
    const float* x     = (const float*)d_in[0];  // [B,T,DIN]
    const float* noise = (const float*)d_in[1];  // [B,T,H]
    const float* Wx    = (const float*)d_in[2];  // [H,DIN]
    const float* bah   = (const float*)d_in[3];  // [H]
    const float* Wh    = (const float*)d_in[4];  // [H,H]
    const float* Wy    = (const float*)d_in[5];  // [DOUT,H]
    const float* ah0   = (const float*)d_in[6];  // [H]

    float* out0   = (float*)d_out;                   // [B,T,DOUT]
    float* hstore = (float*)d_out + BB * TT * DOUTN; // [B,T,H]

    float* WxT = (float*)d_ws;                              // [DIN,H] fp32
    unsigned short* Wp = (unsigned short*)(WxT + DIN * HH); // [512*512] bf16

    transpose_wx<<<(DIN * HH + 255) / 256, 256, 0, stream>>>(Wx, WxT);
    pack_wh<<<16 * 32 * 64 / 256, 256, 0, stream>>>(Wh, Wp);
    x2ah_kernel<<<BB * TT / 16, 256, 0, stream>>>(x, WxT, bah, hstore);
    scan7_kernel<<<BB / 16, 512, 0, stream>>>(Wp, noise, ah0, hstore);
    out_kernel<<<BB * TT / 4, 256, 0, stream>>>(hstore, Wy, out0);
}

// Round 8
// 2203.388 us; speedup vs baseline: 2.1048x; 1.2347x over previous
//
#include <hip/hip_runtime.h>
#include <math.h>

#define BB   512
#define TT   256
#define HH   512
#define DIN  514
#define DOUTN 2
#define DT   0.1f
#define TH   (TT * HH)

typedef short s16x8 __attribute__((ext_vector_type(8)));
typedef float f32x4 __attribute__((ext_vector_type(4)));

__device__ __forceinline__ float retanh_f(float a) {
    float am = fminf(a, 15.0f);
    float E  = __expf(2.0f * am);
    float tp = __fdividef(E - 1.0f, E + 1.0f);
    return a > 0.0f ? tp : 0.0f;
}

__device__ __forceinline__ unsigned short f2bf(float f) {
    unsigned u = __float_as_uint(f);
    unsigned r = (u + 0x7FFFu + ((u >> 16) & 1u)) >> 16;
    return (unsigned short)r;
}

// ---------------------------------------------------------------------------
// Kernel 1a: WxT[d][j] = Wx[j][d]
// ---------------------------------------------------------------------------
__global__ __launch_bounds__(256) void transpose_wx(const float* __restrict__ Wx,
                                                    float* __restrict__ WxT) {
    int idx = blockIdx.x * 256 + threadIdx.x;
    if (idx < DIN * HH) {
        int d = idx / HH, j = idx % HH;
        WxT[idx] = Wx[j * DIN + d];
    }
}

// ---------------------------------------------------------------------------
// Kernel 1b: pack W_h into bf16 MFMA B-fragments (PROVEN rounds 6-7).
// frag f = (kc*32 + jt)*64 + lane, elem e: B[k][j]=Wh[j][k],
//   j = jt*16 + (lane&15), k = kc*32 + (lane>>4)*8 + e.
// ---------------------------------------------------------------------------
__global__ __launch_bounds__(256) void pack_wh(const float* __restrict__ Wh,
                                               unsigned short* __restrict__ Wp) {
    const int idx = blockIdx.x * 256 + threadIdx.x;   // 0..32767
    const int l  = idx & 63;
    const int jt = (idx >> 6) & 31;
    const int kc = idx >> 11;
    const int j  = jt * 16 + (l & 15);
    const int k0 = kc * 32 + (l >> 4) * 8;
    s16x8 pv;
    #pragma unroll
    for (int e = 0; e < 8; ++e) pv[e] = (short)f2bf(Wh[j * HH + k0 + e]);
    *(s16x8*)&Wp[(size_t)idx * 8] = pv;
}

// ---------------------------------------------------------------------------
// Kernel 2: x2ah = x @ WxT + b (fp32; into hstore region, consumed by scan)
// ---------------------------------------------------------------------------
__global__ __launch_bounds__(256) void x2ah_kernel(const float* __restrict__ X,
                                                   const float* __restrict__ WxT,
                                                   const float* __restrict__ bias,
                                                   float* __restrict__ outr) {
    __shared__ float xs[16][516];
    const int tid = threadIdx.x;
    const int r0  = blockIdx.x * 16;

    #pragma unroll
    for (int m = 0; m < 16; ++m) {
        const float* xr = X + (r0 + m) * DIN;
        xs[m][tid]       = xr[tid];
        xs[m][tid + 256] = xr[tid + 256];
        if (tid < 2) xs[m][512 + tid] = xr[512 + tid];
    }
    __syncthreads();

    const int j = 2 * tid;
    const float2 bv = *(const float2*)&bias[j];
    float acc[16][2];
    #pragma unroll
    for (int m = 0; m < 16; ++m) { acc[m][0] = bv.x; acc[m][1] = bv.y; }

    for (int d = 0; d < 512; d += 4) {
        const float2 w0 = *(const float2*)&WxT[(d + 0) * HH + j];
        const float2 w1 = *(const float2*)&WxT[(d + 1) * HH + j];
        const float2 w2 = *(const float2*)&WxT[(d + 2) * HH + j];
        const float2 w3 = *(const float2*)&WxT[(d + 3) * HH + j];
        #pragma unroll
        for (int m = 0; m < 16; ++m) {
            const float4 xv = *(const float4*)&xs[m][d];
            acc[m][0] += xv.x * w0.x; acc[m][1] += xv.x * w0.y;
            acc[m][0] += xv.y * w1.x; acc[m][1] += xv.y * w1.y;
            acc[m][0] += xv.z * w2.x; acc[m][1] += xv.z * w2.y;
            acc[m][0] += xv.w * w3.x; acc[m][1] += xv.w * w3.y;
        }
    }
    {
        const float2 wa = *(const float2*)&WxT[512 * HH + j];
        const float2 wb = *(const float2*)&WxT[513 * HH + j];
        #pragma unroll
        for (int m = 0; m < 16; ++m) {
            acc[m][0] += xs[m][512] * wa.x; acc[m][1] += xs[m][512] * wa.y;
            acc[m][0] += xs[m][513] * wb.x; acc[m][1] += xs[m][513] * wb.y;
        }
    }
    #pragma unroll
    for (int m = 0; m < 16; ++m) {
        *(float2*)&outr[(r0 + m) * HH + j] = make_float2(acc[m][0], acc[m][1]);
    }
}

// ---------------------------------------------------------------------------
// Kernel 3 (Design H2): MFMA scan, W resident — NAMED register fragments.
// 32 WGs x 512 thr, 1 WG/CU, __launch_bounds__(512,2) -> 256 VGPR budget.
// W: kc 4..15 in 48 NAMED s16x8 (192 VGPR, no array -> no scratch);
//    kc 0..3 in 128 KB LDS. h bf16 in LDS [16][520]. x2/nz loaded in the
//    epilogue (after barrier 1) with a 2-deep pipeline (16 live regs max).
// Fragment maps bit-identical to proven rounds 6-7.
// ---------------------------------------------------------------------------
#define WDECL(KC) s16x8 wA##KC, wB##KC, wC##KC, wD##KC

#define WLOAD(KC) do { \
    wA##KC = WpW[((KC) + 4) * 2048 + 0 * 64]; \
    wB##KC = WpW[((KC) + 4) * 2048 + 1 * 64]; \
    wC##KC = WpW[((KC) + 4) * 2048 + 2 * 64]; \
    wD##KC = WpW[((KC) + 4) * 2048 + 3 * 64]; \
} while (0)

#define KSTEP_REG(KC) do { \
    const s16x8 A = *(const s16x8*)&hrow[((KC) + 4) * 32]; \
    acc0 = __builtin_amdgcn_mfma_f32_16x16x32_bf16(A, wA##KC, acc0, 0, 0, 0); \
    acc1 = __builtin_amdgcn_mfma_f32_16x16x32_bf16(A, wB##KC, acc1, 0, 0, 0); \
    acc2 = __builtin_amdgcn_mfma_f32_16x16x32_bf16(A, wC##KC, acc2, 0, 0, 0); \
    acc3 = __builtin_amdgcn_mfma_f32_16x16x32_bf16(A, wD##KC, acc3, 0, 0, 0); \
} while (0)

#define KSTEP_LDS(KC) do { \
    const s16x8 A  = *(const s16x8*)&hrow[(KC) * 32]; \
    const s16x8 B0 = WlW[(KC) * 2048 + 0 * 64]; \
    const s16x8 B1 = WlW[(KC) * 2048 + 1 * 64]; \
    const s16x8 B2 = WlW[(KC) * 2048 + 2 * 64]; \
    const s16x8 B3 = WlW[(KC) * 2048 + 3 * 64]; \
    acc0 = __builtin_amdgcn_mfma_f32_16x16x32_bf16(A, B0, acc0, 0, 0, 0); \
    acc1 = __builtin_amdgcn_mfma_f32_16x16x32_bf16(A, B1, acc1, 0, 0, 0); \
    acc2 = __builtin_amdgcn_mfma_f32_16x16x32_bf16(A, B2, acc2, 0, 0, 0); \
    acc3 = __builtin_amdgcn_mfma_f32_16x16x32_bf16(A, B3, acc3, 0, 0, 0); \
} while (0)

#define LOADN(JN, xv, nv) do { \
    xv.x = hio[gbase + 0 * TH + (JN)]; \
    xv.y = hio[gbase + 1 * TH + (JN)]; \
    xv.z = hio[gbase + 2 * TH + (JN)]; \
    xv.w = hio[gbase + 3 * TH + (JN)]; \
    nv.x = noise[gbase + 0 * TH + (JN)]; \
    nv.y = noise[gbase + 1 * TH + (JN)]; \
    nv.z = noise[gbase + 2 * TH + (JN)]; \
    nv.w = noise[gbase + 3 * TH + (JN)]; \
} while (0)

#define CONSUME(JN, accv, ahv, xv, nv) do { \
    ahv = ahv + DT * (accv + xv - ahv); \
    const float h0 = retanh_f(ahv.x) + nv.x; \
    const float h1 = retanh_f(ahv.y) + nv.y; \
    const float h2 = retanh_f(ahv.z) + nv.z; \
    const float h3 = retanh_f(ahv.w) + nv.w; \
    hio[gbase + 0 * TH + (JN)] = h0; \
    hio[gbase + 1 * TH + (JN)] = h1; \
    hio[gbase + 2 * TH + (JN)] = h2; \
    hio[gbase + 3 * TH + (JN)] = h3; \
    hs[lg4 + 0][JN] = f2bf(h0); \
    hs[lg4 + 1][JN] = f2bf(h1); \
    hs[lg4 + 2][JN] = f2bf(h2); \
    hs[lg4 + 3][JN] = f2bf(h3); \
} while (0)

__global__ __launch_bounds__(512, 2) void scan8_kernel(const unsigned short* __restrict__ Wp,
                                                       const float* __restrict__ noise,
                                                       const float* __restrict__ ah0,
                                                       float* __restrict__ hio) {
    __shared__ __align__(16) unsigned short Wl[4 * 32 * 64 * 8];  // 128 KB: kc 0..3
    __shared__ __align__(16) unsigned short hs[16][520];          // 16.6 KB

    const int tid = threadIdx.x;
    const int l   = tid & 63;
    const int w   = tid >> 6;
    const int lm  = l & 15;
    const int lg  = l >> 4;
    const int lg4 = lg * 4;
    const int b0  = blockIdx.x * 16;

    const s16x8* WpV = (const s16x8*)Wp;
    s16x8* WlV = (s16x8*)Wl;

    // one-time: kc 0..3 into LDS
    for (int idx = tid; idx < 4 * 32 * 64; idx += 512)
        WlV[idx] = WpV[idx];

    // one-time: kc 4..15 into 48 NAMED registers
    const s16x8* WpW = WpV + (size_t)(4 * w) * 64 + l;
    WDECL(0);  WDECL(1);  WDECL(2);  WDECL(3);
    WDECL(4);  WDECL(5);  WDECL(6);  WDECL(7);
    WDECL(8);  WDECL(9);  WDECL(10); WDECL(11);
    WLOAD(0);  WLOAD(1);  WLOAD(2);  WLOAD(3);
    WLOAD(4);  WLOAD(5);  WLOAD(6);  WLOAD(7);
    WLOAD(8);  WLOAD(9);  WLOAD(10); WLOAD(11);

    const int jn0 = (4 * w + 0) * 16 + lm;
    const int jn1 = (4 * w + 1) * 16 + lm;
    const int jn2 = (4 * w + 2) * 16 + lm;
    const int jn3 = (4 * w + 3) * 16 + lm;

    f32x4 ahv0, ahv1, ahv2, ahv3;
    {
        const float a0 = ah0[jn0], a1 = ah0[jn1], a2 = ah0[jn2], a3 = ah0[jn3];
        ahv0 = (f32x4){a0, a0, a0, a0};
        ahv1 = (f32x4){a1, a1, a1, a1};
        ahv2 = (f32x4){a2, a2, a2, a2};
        ahv3 = (f32x4){a3, a3, a3, a3};
    }

    // init h(t=0) = retanh(ah0), same for all batch rows
    for (int idx = tid; idx < 16 * 512; idx += 512) {
        int b = idx >> 9, k = idx & 511;
        hs[b][k] = f2bf(retanh_f(ah0[k]));
    }
    __syncthreads();

    const unsigned short* hrow = &hs[lm][lg * 8];
    const s16x8* WlW = WlV + (size_t)(4 * w) * 64 + l;

    int gbase = (b0 + lg4) * TH;   // + t*HH added incrementally

    for (int t = 0; t < TT; ++t) {
        f32x4 acc0 = (f32x4){0.f, 0.f, 0.f, 0.f};
        f32x4 acc1 = (f32x4){0.f, 0.f, 0.f, 0.f};
        f32x4 acc2 = (f32x4){0.f, 0.f, 0.f, 0.f};
        f32x4 acc3 = (f32x4){0.f, 0.f, 0.f, 0.f};

        KSTEP_LDS(0);  KSTEP_LDS(1);  KSTEP_LDS(2);  KSTEP_LDS(3);
        KSTEP_REG(0);  KSTEP_REG(1);  KSTEP_REG(2);  KSTEP_REG(3);
        KSTEP_REG(4);  KSTEP_REG(5);  KSTEP_REG(6);  KSTEP_REG(7);
        KSTEP_REG(8);  KSTEP_REG(9);  KSTEP_REG(10); KSTEP_REG(11);

        __syncthreads();   // all reads of hs(t) complete

        // epilogue: 2-deep load pipeline over j-tiles
        {
            f32x4 x2a, nza, x2b, nzb;
            LOADN(jn0, x2a, nza);
            LOADN(jn1, x2b, nzb);
            CONSUME(jn0, acc0, ahv0, x2a, nza);
            LOADN(jn2, x2a, nza);
            CONSUME(jn1, acc1, ahv1, x2b, nzb);
            LOADN(jn3, x2b, nzb);
            CONSUME(jn2, acc2, ahv2, x2a, nza);
            CONSUME(jn3, acc3, ahv3, x2b, nzb);
        }
        gbase += HH;
        __syncthreads();   // hs(t+1) complete before next step's reads
    }
}

// ---------------------------------------------------------------------------
// Kernel 4: tiny output projection
// ---------------------------------------------------------------------------
__global__ __launch_bounds__(256) void out_kernel(const float* __restrict__ hstore,
                                                  const float* __restrict__ Wy,
                                                  float* __restrict__ out0) {
    const int wave = threadIdx.x >> 6;
    const int lane = threadIdx.x & 63;
    const int r = blockIdx.x * 4 + wave;

    const float4* hv4 = (const float4*)&hstore[r * HH];
    float a0 = 0.0f, a1 = 0.0f;
    #pragma unroll
    for (int u = 0; u < 2; ++u) {
        const int e = u * 64 + lane;
        const float4 h  = hv4[e];
        const float4 w0 = *(const float4*)&Wy[e * 4];
        const float4 w1 = *(const float4*)&Wy[HH + e * 4];
        a0 += h.x * w0.x + h.y * w0.y + h.z * w0.z + h.w * w0.w;
        a1 += h.x * w1.x + h.y * w1.y + h.z * w1.z + h.w * w1.w;
    }
    #pragma unroll
    for (int off = 32; off > 0; off >>= 1) {
        a0 += __shfl_xor(a0, off);
        a1 += __shfl_xor(a1, off);
    }
    if (lane == 0) {
        out0[r * 2]     = a0;
        out0[r * 2 + 1] = a1;
    }
}

// ---------------------------------------------------------------------------
extern "C" void kernel_launch(void* const* d_in, const int* in_sizes, int n_in,
                              void* d_out, int out_size, void* d_ws, size_t ws_size,
                              hipStream_t stream) {
    const float* x     = (const float*)d_in[0];  // [B,T,DIN]
    const float* noise = (const float*)d_in[1];  // [B,T,H]
    const float* Wx    = (const float*)d_in[2];  // [H,DIN]
    const float* bah   = (const float*)d_in[3];  // [H]
    const float* Wh    = (const float*)d_in[4];  // [H,H]
    const float* Wy    = (const float*)d_in[5];  // [DOUT,H]
    const float* ah0   = (const float*)d_in[6];  // [H]

    float* out0   = (float*)d_out;                   // [B,T,DOUT]
    float* hstore = (float*)d_out + BB * TT * DOUTN; // [B,T,H]

    float* WxT = (float*)d_ws;                              // [DIN,H] fp32
    unsigned short* Wp = (unsigned short*)(WxT + DIN * HH); // [512*512] bf16

    transpose_wx<<<(DIN * HH + 255) / 256, 256, 0, stream>>>(Wx, WxT);
    pack_wh<<<16 * 32 * 64 / 256, 256, 0, stream>>>(Wh, Wp);
    x2ah_kernel<<<BB * TT / 16, 256, 0, stream>>>(x, WxT, bah, hstore);
    scan8_kernel<<<BB / 16, 512, 0, stream>>>(Wp, noise, ah0, hstore);
    out_kernel<<<BB * TT / 4, 256, 0, stream>>>(hstore, Wy, out0);
}